// Round 19
// baseline (81.474 us; speedup 1.0000x reference)
//
#include <hip/hip_runtime.h>

// GCN 2-layer forward via two-level dst sort (fixed-cap bins -> in-place counting sort)
// + register gather. bin = dst>>8 (256 nodes/bin, 391 bins), record = (src<<8)|(dst&255).
// Layer-1 algebra: A_norm @ (x@W1) == (A_norm@x) @ W1 (3-float payload).
// Round19: r17 geometry + 8-way striped per-bin cursors (same-address atomic chain
// 391 -> 49 deep) + reservation issued BEFORE the prefix scan (latency hidden).

#define CHUNK  8192
#define NBIT   8
#define BSZ    256
#define BMSK   255
#define SUBCAP 1280            // per (bin,stripe): mean 1024, +8 sigma
#define CAP    (8 * SUBCAP)    // 10240 dwords per bin region

__global__ void k_zero(int* __restrict__ gcursor, int n) {
    for (int i = threadIdx.x; i < n; i += 1024) gcursor[i] = 0;
}

__global__ void k_scatter(const int* __restrict__ src, const int* __restrict__ dst,
                          int* __restrict__ gcursor, int* __restrict__ records,
                          int E, int nbins) {
    __shared__ int cnt[512];
    __shared__ int loff[512];        // inclusive scan
    __shared__ int gw[512];          // global write pos - local exclusive offset
    __shared__ int stage[CHUNK];     // 32 KB
    __shared__ unsigned short sbin[CHUNK];  // 16 KB
    int t = threadIdx.x;             // 512 threads
    int b = blockIdx.x;
    int stripe = b & 7;
    cnt[t] = 0;
    __syncthreads();
    int e0 = b * CHUNK;
    int n = min(CHUNK, E - e0);
    int nv = n >> 2;                 // chunk sizes are multiples of 4
    const int4* s4p = (const int4*)(src + e0);
    const int4* d4p = (const int4*)(dst + e0);
    int4 dv0, dv1, dv2, dv3, sv0, sv1, sv2, sv3;
    int ra0,rb0,rc0,rd0, ra1,rb1,rc1,rd1, ra2,rb2,rc2,rd2, ra3,rb3,rc3,rd3;
#define LOADIT(K) { int idx = t + (K << 9); if (idx < nv) { dv##K = d4p[idx]; sv##K = s4p[idx]; \
        ra##K = atomicAdd(&cnt[dv##K.x >> NBIT], 1); \
        rb##K = atomicAdd(&cnt[dv##K.y >> NBIT], 1); \
        rc##K = atomicAdd(&cnt[dv##K.z >> NBIT], 1); \
        rd##K = atomicAdd(&cnt[dv##K.w >> NBIT], 1); } }
    LOADIT(0) LOADIT(1) LOADIT(2) LOADIT(3)
#undef LOADIT
    __syncthreads();
    // reservation FIRST (latency of the 49-deep same-address chain hides under the scan)
    int c = 0, gb = 0;
    if (t < nbins) {
        c = cnt[t];
        if (c > 0) gb = atomicAdd(&gcursor[t * 8 + stripe], c);
    }
    loff[t] = cnt[t];
    __syncthreads();
    for (int d = 1; d < 512; d <<= 1) {
        int a0 = (t >= d) ? loff[t - d] : 0;
        __syncthreads();
        loff[t] += a0;
        __syncthreads();
    }
    if (t < nbins && c > 0)
        gw[t] = t * CAP + stripe * SUBCAP + gb - (loff[t] - c);
#define PLACE(DD, SS, RK) { int b_ = (DD) >> NBIT; int slot = (loff[b_] - cnt[b_]) + (RK); \
        stage[slot] = ((SS) << NBIT) | ((DD) & BMSK); sbin[slot] = (unsigned short)b_; }
#define STAGEIT(K) { int idx = t + (K << 9); if (idx < nv) { \
        PLACE(dv##K.x, sv##K.x, ra##K) PLACE(dv##K.y, sv##K.y, rb##K) \
        PLACE(dv##K.z, sv##K.z, rc##K) PLACE(dv##K.w, sv##K.w, rd##K) } }
    STAGEIT(0) STAGEIT(1) STAGEIT(2) STAGEIT(3)
#undef STAGEIT
#undef PLACE
    __syncthreads();
#pragma unroll
    for (int it = 0; it < 16; ++it) {
        int i = t + (it << 9);
        if (i < n) records[gw[sbin[i]] + i] = stage[i];
    }
}

// per bin (512 thr): 8 striped segments -> rank via atomic-return, scan -> u4/off/dend
// (x staged via LDS), re-read segments placing into LDS rbuf2, stream compact csr out
// as int4 at the bin region base. csr aliases records.
__global__ void k_sort(int* __restrict__ records /* = csr out */,
                       const int* __restrict__ gcursor, const float* __restrict__ x,
                       float4* __restrict__ u4, int* __restrict__ off,
                       int* __restrict__ dend, int N) {
    __shared__ int h[BSZ];
    __shared__ int sc[BSZ];
    __shared__ int base[BSZ];              // local exclusive offset
    __shared__ int sfill[8];
    __shared__ int sbase[8];
    __shared__ unsigned short rrank[CAP];  // 20 KB
    __shared__ int rbuf2[CAP];             // 40 KB
    __shared__ float sx[3 * BSZ];          // 3 KB
    int b = blockIdx.x, t = threadIdx.x;   // 512 threads
    if (t < BSZ) h[t] = 0;
    if (t < 8) sfill[t] = min(gcursor[b * 8 + t], SUBCAP);
    int node0 = b << NBIT;
    int xn = min(3 * BSZ, 3 * (N - node0));
    for (int i = t; i < xn; i += 512) sx[i] = x[3 * node0 + i];
    __syncthreads();
    if (t == 0) {
        int acc = 0;
#pragma unroll
        for (int s = 0; s < 8; ++s) { sbase[s] = acc; acc += sfill[s]; }
    }
    __syncthreads();
    int r0 = b * CAP;
    // phase 1: rank each segment (int4 reads; SUBCAP%4==0 keeps 16B alignment)
#pragma unroll
    for (int s = 0; s < 8; ++s) {
        int f = sfill[s], nv = f >> 2, lin = sbase[s];
        const int4* rp = (const int4*)(records + r0 + s * SUBCAP);
        for (int v = t; v < nv; v += 512) {
            int4 r4 = rp[v];
            int ib = lin + (v << 2);
            rrank[ib]     = (unsigned short)atomicAdd(&h[r4.x & BMSK], 1);
            rrank[ib + 1] = (unsigned short)atomicAdd(&h[r4.y & BMSK], 1);
            rrank[ib + 2] = (unsigned short)atomicAdd(&h[r4.z & BMSK], 1);
            rrank[ib + 3] = (unsigned short)atomicAdd(&h[r4.w & BMSK], 1);
        }
        for (int i = (nv << 2) + t; i < f; i += 512)
            rrank[lin + i] = (unsigned short)atomicAdd(&h[records[r0 + s * SUBCAP + i] & BMSK], 1);
    }
    __syncthreads();
    if (t < BSZ) sc[t] = h[t];
    __syncthreads();
    for (int d = 1; d < BSZ; d <<= 1) {
        int v = (t < BSZ && t >= d) ? sc[t - d] : 0;
        __syncthreads();
        if (t < BSZ) sc[t] += v;
        __syncthreads();
    }
    int node = node0 + t;
    if (t < BSZ) {
        int excl = sc[t] - h[t];
        base[t] = excl;
        if (node < N) {
            off[node]  = r0 + excl;
            dend[node] = r0 + excl + h[t];
            float di = rsqrtf((float)(h[t] + 1));    // +1 self-loop
            u4[node] = make_float4(sx[3*t] * di, sx[3*t+1] * di, sx[3*t+2] * di, di);
        }
    }
    __syncthreads();
    // phase 3: place into LDS (scattered writes hit LDS, not L2)
#pragma unroll
    for (int s = 0; s < 8; ++s) {
        int f = sfill[s], nv = f >> 2, lin = sbase[s];
        const int4* rp = (const int4*)(records + r0 + s * SUBCAP);
        for (int v = t; v < nv; v += 512) {
            int4 r4 = rp[v];
            int ib = lin + (v << 2);
            rbuf2[base[r4.x & BMSK] + rrank[ib]]     = r4.x >> NBIT;
            rbuf2[base[r4.y & BMSK] + rrank[ib + 1]] = r4.y >> NBIT;
            rbuf2[base[r4.z & BMSK] + rrank[ib + 2]] = r4.z >> NBIT;
            rbuf2[base[r4.w & BMSK] + rrank[ib + 3]] = r4.w >> NBIT;
        }
        for (int i = (nv << 2) + t; i < f; i += 512) {
            int r = records[r0 + s * SUBCAP + i];
            rbuf2[base[r & BMSK] + rrank[lin + i]] = r >> NBIT;
        }
    }
    __syncthreads();
    // stream compact csr out, int4-coalesced
    int count = sbase[7] + sfill[7];
    int nv = count >> 2;
    int4* wp = (int4*)(records + r0);
    for (int v = t; v < nv; v += 512) {
        int ib = v << 2;
        wp[v] = make_int4(rbuf2[ib], rbuf2[ib + 1], rbuf2[ib + 2], rbuf2[ib + 3]);
    }
    for (int i = (nv << 2) + t; i < count; i += 512) records[r0 + i] = rbuf2[i];
}

// 8 lanes per node, 4-deep ILP, shfl_xor octet reduce; MLP parallel across lanes:
// v=(acc+self)*dinv; h=v@W1+b1 (2 units/lane); relu; g2=(h@W2)*dinv
__global__ void k_gat1(const int* __restrict__ off, const int* __restrict__ dend,
                       const int* __restrict__ csr, const float4* __restrict__ u4,
                       const float* __restrict__ W1, const float* __restrict__ b1,
                       const float* __restrict__ W2, float2* __restrict__ g2, int N) {
    __shared__ float sW1[48];
    __shared__ float sb1[16];
    __shared__ float sW2[32];
    if (threadIdx.x < 48) sW1[threadIdx.x] = W1[threadIdx.x];
    if (threadIdx.x < 16) sb1[threadIdx.x] = b1[threadIdx.x];
    if (threadIdx.x < 32) sW2[threadIdx.x] = W2[threadIdx.x];
    __syncthreads();
    int gid = blockIdx.x * blockDim.x + threadIdx.x;
    int node = gid >> 3, q = gid & 7;
    if (node >= N) return;
    int o0 = off[node], o1 = dend[node];
    float a0 = 0.f, a1 = 0.f, a2 = 0.f;
    int j = o0 + q;
    for (; j + 24 < o1; j += 32) {
        int s[4]; float4 v[4];
#pragma unroll
        for (int k = 0; k < 4; ++k) s[k] = csr[j + 8*k];
#pragma unroll
        for (int k = 0; k < 4; ++k) v[k] = u4[s[k]];
#pragma unroll
        for (int k = 0; k < 4; ++k) { a0 += v[k].x; a1 += v[k].y; a2 += v[k].z; }
    }
    for (; j < o1; j += 8) {
        float4 v = u4[csr[j]];
        a0 += v.x; a1 += v.y; a2 += v.z;
    }
    a0 += __shfl_xor(a0, 1); a0 += __shfl_xor(a0, 2); a0 += __shfl_xor(a0, 4);
    a1 += __shfl_xor(a1, 1); a1 += __shfl_xor(a1, 2); a1 += __shfl_xor(a1, 4);
    a2 += __shfl_xor(a2, 1); a2 += __shfl_xor(a2, 2); a2 += __shfl_xor(a2, 4);
    float4 self = u4[node];           // same addr across octet -> broadcast
    float di = self.w;
    float v0 = (a0 + self.x) * di, v1 = (a1 + self.y) * di, v2 = (a2 + self.z) * di;
    float p0 = 0.f, p1 = 0.f;
#pragma unroll
    for (int kk = 0; kk < 2; ++kk) {
        int k = q + (kk << 3);        // lane q covers hidden units q and q+8
        float tt = fmaxf(v0 * sW1[k] + v1 * sW1[16 + k] + v2 * sW1[32 + k] + sb1[k], 0.f);
        p0 += tt * sW2[2*k];
        p1 += tt * sW2[2*k + 1];
    }
    p0 += __shfl_xor(p0, 1); p0 += __shfl_xor(p0, 2); p0 += __shfl_xor(p0, 4);
    p1 += __shfl_xor(p1, 1); p1 += __shfl_xor(p1, 2); p1 += __shfl_xor(p1, 4);
    if (q == 0) g2[node] = make_float2(p0 * di, p1 * di);
}

// 8 lanes per node: accumulate g2[src] (4-deep), octet reduce, fused log_softmax
__global__ void k_gat2(const int* __restrict__ off, const int* __restrict__ dend,
                       const int* __restrict__ csr, const float2* __restrict__ g2,
                       const float4* __restrict__ u4, const float* __restrict__ b2,
                       float2* __restrict__ out, int N) {
    int gid = blockIdx.x * blockDim.x + threadIdx.x;
    int node = gid >> 3, q = gid & 7;
    if (node >= N) return;
    int o0 = off[node], o1 = dend[node];
    float a0 = 0.f, a1 = 0.f;
    int j = o0 + q;
    for (; j + 24 < o1; j += 32) {
        int s[4]; float2 v[4];
#pragma unroll
        for (int k = 0; k < 4; ++k) s[k] = csr[j + 8*k];
#pragma unroll
        for (int k = 0; k < 4; ++k) v[k] = g2[s[k]];
#pragma unroll
        for (int k = 0; k < 4; ++k) { a0 += v[k].x; a1 += v[k].y; }
    }
    for (; j < o1; j += 8) {
        float2 v = g2[csr[j]];
        a0 += v.x; a1 += v.y;
    }
    a0 += __shfl_xor(a0, 1); a0 += __shfl_xor(a0, 2); a0 += __shfl_xor(a0, 4);
    a1 += __shfl_xor(a1, 1); a1 += __shfl_xor(a1, 2); a1 += __shfl_xor(a1, 4);
    if (q != 0) return;
    float2 self = g2[node];
    float di = u4[node].w;
    float o0f = (a0 + self.x) * di + b2[0];
    float o1f = (a1 + self.y) * di + b2[1];
    float m = fmaxf(o0f, o1f);
    float lse = m + logf(expf(o0f - m) + expf(o1f - m));
    out[node] = make_float2(o0f - lse, o1f - lse);
}

extern "C" void kernel_launch(void* const* d_in, const int* in_sizes, int n_in,
                              void* d_out, int out_size, void* d_ws, size_t ws_size,
                              hipStream_t stream) {
    const float* x  = (const float*)d_in[0];
    const int*   ei = (const int*)d_in[1];
    const float* W1 = (const float*)d_in[2];
    const float* b1 = (const float*)d_in[3];
    const float* W2 = (const float*)d_in[4];
    const float* b2 = (const float*)d_in[5];
    float* out = (float*)d_out;

    const int N = in_sizes[0] / 3;
    const int E = in_sizes[1] / 2;
    const int* src = ei;
    const int* dst = ei + E;
    const int nbins = (N + BSZ - 1) >> NBIT;      // 391
    const int nbC = (E + CHUNK - 1) / CHUNK;      // 391
    const int ncur = nbins * 8;                   // striped cursors

    // ws (dwords): [gcursor ncur(pad 3328)][off N+8][dend N][records/csr nbins*CAP][u4 4N][g2 2N]
    //  ~= 13KB + 0.4MB + 0.4MB + 16MB + 1.6MB + 0.8MB ~= 19.2 MB
    int* gcursor  = (int*)d_ws;
    int* off      = gcursor + 3328;
    int* dend     = off + N + 8;
    int* records  = dend + N;                     // doubles as csr
    float4* u4    = (float4*)(records + (size_t)nbins * CAP);
    float2* g2    = (float2*)(u4 + N);

    k_zero<<<1, 1024, 0, stream>>>(gcursor, ncur);
    k_scatter<<<nbC, 512, 0, stream>>>(src, dst, gcursor, records, E, nbins);
    k_sort<<<nbins, 512, 0, stream>>>(records, gcursor, x, u4, off, dend, N);
    int nbG = ((N * 8) + 255) / 256;
    k_gat1<<<nbG, 256, 0, stream>>>(off, dend, records, u4, W1, b1, W2, g2, N);
    k_gat2<<<nbG, 256, 0, stream>>>(off, dend, records, g2, u4, b2, (float2*)out, N);
}

// Round 20
// 76.300 us; speedup vs baseline: 1.0678x; 1.0678x over previous
//
#include <hip/hip_runtime.h>

// GCN 2-layer forward via two-level dst sort (fixed-cap bins -> in-place counting sort)
// + register gather. bin = dst>>8 (256 nodes/bin), record = (src<<8)|(dst&255).
// Layer-1 algebra: A_norm @ (x@W1) == (A_norm@x) @ W1 (3-float payload).
// Round20: revert to round-17 configuration — measured optimum (76.6 us).
// Falsified levers: CSR-build atomics (r2), payload-size (r3), LDS bank conflicts (r7),
// atomic-return ranks (r12, kept), coalescing (r13, kept), memset node (r14, kept),
// coop fusion (r15/16, XCD-incoherent), gather TLP (r17), balance (r18), stripes (r19).

#define CHUNK 8192
#define NBIT  8
#define BSZ   256
#define BMSK  255
#define CAP   12288   // dwords per bin region; mean fill 8192 -> huge margin

__global__ void k_zero(int* __restrict__ gcursor) {
    gcursor[threadIdx.x] = 0;     // 512 threads, 1 block
}

__global__ void k_scatter(const int* __restrict__ src, const int* __restrict__ dst,
                          int* __restrict__ gcursor, int* __restrict__ records,
                          int E, int nbins) {
    __shared__ int cnt[512];
    __shared__ int loff[512];        // inclusive scan
    __shared__ int gw[512];          // global write base - local exclusive offset
    __shared__ int stage[CHUNK];     // 32 KB
    __shared__ unsigned short sbin[CHUNK];  // 16 KB
    int t = threadIdx.x;             // 512 threads
    cnt[t] = 0;
    __syncthreads();
    int e0 = blockIdx.x * CHUNK;
    int n = min(CHUNK, E - e0);
    int nv = n >> 2;                 // chunk sizes are multiples of 4
    const int4* s4p = (const int4*)(src + e0);
    const int4* d4p = (const int4*)(dst + e0);
    int4 dv0, dv1, dv2, dv3, sv0, sv1, sv2, sv3;
    int ra0,rb0,rc0,rd0, ra1,rb1,rc1,rd1, ra2,rb2,rc2,rd2, ra3,rb3,rc3,rd3;
#define LOADIT(K) { int idx = t + (K << 9); if (idx < nv) { dv##K = d4p[idx]; sv##K = s4p[idx]; \
        ra##K = atomicAdd(&cnt[dv##K.x >> NBIT], 1); \
        rb##K = atomicAdd(&cnt[dv##K.y >> NBIT], 1); \
        rc##K = atomicAdd(&cnt[dv##K.z >> NBIT], 1); \
        rd##K = atomicAdd(&cnt[dv##K.w >> NBIT], 1); } }
    LOADIT(0) LOADIT(1) LOADIT(2) LOADIT(3)
#undef LOADIT
    __syncthreads();
    loff[t] = cnt[t];
    __syncthreads();
    for (int d = 1; d < 512; d <<= 1) {
        int a0 = (t >= d) ? loff[t - d] : 0;
        __syncthreads();
        loff[t] += a0;
        __syncthreads();
    }
    if (t < nbins) {
        int c = cnt[t];
        if (c > 0) {
            int gb = t * CAP + atomicAdd(&gcursor[t], c);
            gw[t] = gb - (loff[t] - c);
        }
    }
#define PLACE(DD, SS, RK) { int b_ = (DD) >> NBIT; int slot = (loff[b_] - cnt[b_]) + (RK); \
        stage[slot] = ((SS) << NBIT) | ((DD) & BMSK); sbin[slot] = (unsigned short)b_; }
#define STAGEIT(K) { int idx = t + (K << 9); if (idx < nv) { \
        PLACE(dv##K.x, sv##K.x, ra##K) PLACE(dv##K.y, sv##K.y, rb##K) \
        PLACE(dv##K.z, sv##K.z, rc##K) PLACE(dv##K.w, sv##K.w, rd##K) } }
    STAGEIT(0) STAGEIT(1) STAGEIT(2) STAGEIT(3)
#undef STAGEIT
#undef PLACE
    __syncthreads();
#pragma unroll
    for (int it = 0; it < 16; ++it) {
        int i = t + (it << 9);
        if (i < n) records[gw[sbin[i]] + i] = stage[i];
    }
}

// per bin (512 thr): rank via atomic-return (phase1, int4 reads), scan -> u4/off/dend
// (x staged via LDS), re-read records (L2-hot) placing into LDS rbuf2, stream csr
// out coalesced as int4. csr aliases records.
__global__ void k_sort(int* __restrict__ records /* = csr out */,
                       const int* __restrict__ gcursor, const float* __restrict__ x,
                       float4* __restrict__ u4, int* __restrict__ off,
                       int* __restrict__ dend, int N) {
    __shared__ int h[BSZ];
    __shared__ int sc[BSZ];
    __shared__ int base[BSZ];              // local exclusive offset
    __shared__ unsigned short rrank[CAP];  // 24 KB
    __shared__ int rbuf2[CAP];             // 48 KB
    __shared__ float sx[3 * BSZ];          // 3 KB
    int b = blockIdx.x, t = threadIdx.x;   // 512 threads
    if (t < BSZ) h[t] = 0;
    int node0 = b << NBIT;
    int xn = min(3 * BSZ, 3 * (N - node0));
    for (int i = t; i < xn; i += 512) sx[i] = x[3 * node0 + i];
    __syncthreads();
    int r0 = b * CAP;
    int count = min(gcursor[b], CAP);
    int nv = count >> 2;
    const int4* rp = (const int4*)(records + r0);   // r0 16B-aligned (CAP%4==0)
    for (int v = t; v < nv; v += 512) {
        int4 r4 = rp[v];
        int ib = v << 2;
        rrank[ib]     = (unsigned short)atomicAdd(&h[r4.x & BMSK], 1);
        rrank[ib + 1] = (unsigned short)atomicAdd(&h[r4.y & BMSK], 1);
        rrank[ib + 2] = (unsigned short)atomicAdd(&h[r4.z & BMSK], 1);
        rrank[ib + 3] = (unsigned short)atomicAdd(&h[r4.w & BMSK], 1);
    }
    for (int i = (nv << 2) + t; i < count; i += 512)
        rrank[i] = (unsigned short)atomicAdd(&h[records[r0 + i] & BMSK], 1);
    __syncthreads();
    if (t < BSZ) sc[t] = h[t];
    __syncthreads();
    for (int d = 1; d < BSZ; d <<= 1) {
        int v = (t < BSZ && t >= d) ? sc[t - d] : 0;
        __syncthreads();
        if (t < BSZ) sc[t] += v;
        __syncthreads();
    }
    int node = node0 + t;
    if (t < BSZ) {
        int excl = sc[t] - h[t];
        base[t] = excl;
        if (node < N) {
            off[node]  = r0 + excl;
            dend[node] = r0 + excl + h[t];
            float di = rsqrtf((float)(h[t] + 1));    // +1 self-loop
            u4[node] = make_float4(sx[3*t] * di, sx[3*t+1] * di, sx[3*t+2] * di, di);
        }
    }
    __syncthreads();
    for (int v = t; v < nv; v += 512) {
        int4 r4 = rp[v];
        int ib = v << 2;
        rbuf2[base[r4.x & BMSK] + rrank[ib]]     = r4.x >> NBIT;
        rbuf2[base[r4.y & BMSK] + rrank[ib + 1]] = r4.y >> NBIT;
        rbuf2[base[r4.z & BMSK] + rrank[ib + 2]] = r4.z >> NBIT;
        rbuf2[base[r4.w & BMSK] + rrank[ib + 3]] = r4.w >> NBIT;
    }
    for (int i = (nv << 2) + t; i < count; i += 512) {
        int r = records[r0 + i];
        rbuf2[base[r & BMSK] + rrank[i]] = r >> NBIT;
    }
    __syncthreads();
    int4* wp = (int4*)(records + r0);
    for (int v = t; v < nv; v += 512) {
        int ib = v << 2;
        wp[v] = make_int4(rbuf2[ib], rbuf2[ib + 1], rbuf2[ib + 2], rbuf2[ib + 3]);
    }
    for (int i = (nv << 2) + t; i < count; i += 512) records[r0 + i] = rbuf2[i];
}

// 8 lanes per node, 4-deep ILP, shfl_xor octet reduce; MLP parallel across lanes:
// v=(acc+self)*dinv; h=v@W1+b1 (2 units/lane); relu; g2=(h@W2)*dinv
__global__ void k_gat1(const int* __restrict__ off, const int* __restrict__ dend,
                       const int* __restrict__ csr, const float4* __restrict__ u4,
                       const float* __restrict__ W1, const float* __restrict__ b1,
                       const float* __restrict__ W2, float2* __restrict__ g2, int N) {
    __shared__ float sW1[48];
    __shared__ float sb1[16];
    __shared__ float sW2[32];
    if (threadIdx.x < 48) sW1[threadIdx.x] = W1[threadIdx.x];
    if (threadIdx.x < 16) sb1[threadIdx.x] = b1[threadIdx.x];
    if (threadIdx.x < 32) sW2[threadIdx.x] = W2[threadIdx.x];
    __syncthreads();
    int gid = blockIdx.x * blockDim.x + threadIdx.x;
    int node = gid >> 3, q = gid & 7;
    if (node >= N) return;
    int o0 = off[node], o1 = dend[node];
    float a0 = 0.f, a1 = 0.f, a2 = 0.f;
    int j = o0 + q;
    for (; j + 24 < o1; j += 32) {
        int s[4]; float4 v[4];
#pragma unroll
        for (int k = 0; k < 4; ++k) s[k] = csr[j + 8*k];
#pragma unroll
        for (int k = 0; k < 4; ++k) v[k] = u4[s[k]];
#pragma unroll
        for (int k = 0; k < 4; ++k) { a0 += v[k].x; a1 += v[k].y; a2 += v[k].z; }
    }
    for (; j < o1; j += 8) {
        float4 v = u4[csr[j]];
        a0 += v.x; a1 += v.y; a2 += v.z;
    }
    a0 += __shfl_xor(a0, 1); a0 += __shfl_xor(a0, 2); a0 += __shfl_xor(a0, 4);
    a1 += __shfl_xor(a1, 1); a1 += __shfl_xor(a1, 2); a1 += __shfl_xor(a1, 4);
    a2 += __shfl_xor(a2, 1); a2 += __shfl_xor(a2, 2); a2 += __shfl_xor(a2, 4);
    float4 self = u4[node];           // same addr across octet -> broadcast
    float di = self.w;
    float v0 = (a0 + self.x) * di, v1 = (a1 + self.y) * di, v2 = (a2 + self.z) * di;
    float p0 = 0.f, p1 = 0.f;
#pragma unroll
    for (int kk = 0; kk < 2; ++kk) {
        int k = q + (kk << 3);        // lane q covers hidden units q and q+8
        float tt = fmaxf(v0 * sW1[k] + v1 * sW1[16 + k] + v2 * sW1[32 + k] + sb1[k], 0.f);
        p0 += tt * sW2[2*k];
        p1 += tt * sW2[2*k + 1];
    }
    p0 += __shfl_xor(p0, 1); p0 += __shfl_xor(p0, 2); p0 += __shfl_xor(p0, 4);
    p1 += __shfl_xor(p1, 1); p1 += __shfl_xor(p1, 2); p1 += __shfl_xor(p1, 4);
    if (q == 0) g2[node] = make_float2(p0 * di, p1 * di);
}

// 8 lanes per node: accumulate g2[src] (4-deep), octet reduce, fused log_softmax
__global__ void k_gat2(const int* __restrict__ off, const int* __restrict__ dend,
                       const int* __restrict__ csr, const float2* __restrict__ g2,
                       const float4* __restrict__ u4, const float* __restrict__ b2,
                       float2* __restrict__ out, int N) {
    int gid = blockIdx.x * blockDim.x + threadIdx.x;
    int node = gid >> 3, q = gid & 7;
    if (node >= N) return;
    int o0 = off[node], o1 = dend[node];
    float a0 = 0.f, a1 = 0.f;
    int j = o0 + q;
    for (; j + 24 < o1; j += 32) {
        int s[4]; float2 v[4];
#pragma unroll
        for (int k = 0; k < 4; ++k) s[k] = csr[j + 8*k];
#pragma unroll
        for (int k = 0; k < 4; ++k) v[k] = g2[s[k]];
#pragma unroll
        for (int k = 0; k < 4; ++k) { a0 += v[k].x; a1 += v[k].y; }
    }
    for (; j < o1; j += 8) {
        float2 v = g2[csr[j]];
        a0 += v.x; a1 += v.y;
    }
    a0 += __shfl_xor(a0, 1); a0 += __shfl_xor(a0, 2); a0 += __shfl_xor(a0, 4);
    a1 += __shfl_xor(a1, 1); a1 += __shfl_xor(a1, 2); a1 += __shfl_xor(a1, 4);
    if (q != 0) return;
    float2 self = g2[node];
    float di = u4[node].w;
    float o0f = (a0 + self.x) * di + b2[0];
    float o1f = (a1 + self.y) * di + b2[1];
    float m = fmaxf(o0f, o1f);
    float lse = m + logf(expf(o0f - m) + expf(o1f - m));
    out[node] = make_float2(o0f - lse, o1f - lse);
}

extern "C" void kernel_launch(void* const* d_in, const int* in_sizes, int n_in,
                              void* d_out, int out_size, void* d_ws, size_t ws_size,
                              hipStream_t stream) {
    const float* x  = (const float*)d_in[0];
    const int*   ei = (const int*)d_in[1];
    const float* W1 = (const float*)d_in[2];
    const float* b1 = (const float*)d_in[3];
    const float* W2 = (const float*)d_in[4];
    const float* b2 = (const float*)d_in[5];
    float* out = (float*)d_out;

    const int N = in_sizes[0] / 3;
    const int E = in_sizes[1] / 2;
    const int* src = ei;
    const int* dst = ei + E;
    const int nbins = (N + BSZ - 1) >> NBIT;      // 391
    const int nbC = (E + CHUNK - 1) / CHUNK;      // 391

    // ws (dwords): [gcursor 512][off N+8][dend N][records/csr nbins*CAP][u4 4N][g2 2N]
    int* gcursor  = (int*)d_ws;
    int* off      = gcursor + 512;
    int* dend     = off + N + 8;
    int* records  = dend + N;                     // doubles as csr
    float4* u4    = (float4*)(records + (size_t)nbins * CAP);
    float2* g2    = (float2*)(u4 + N);

    k_zero<<<1, 512, 0, stream>>>(gcursor);
    k_scatter<<<nbC, 512, 0, stream>>>(src, dst, gcursor, records, E, nbins);
    k_sort<<<nbins, 512, 0, stream>>>(records, gcursor, x, u4, off, dend, N);
    int nbG = ((N * 8) + 255) / 256;
    k_gat1<<<nbG, 256, 0, stream>>>(off, dend, records, u4, W1, b1, W2, g2, N);
    k_gat2<<<nbG, 256, 0, stream>>>(off, dend, records, g2, u4, b2, (float2*)out, N);
}